// Round 24
// baseline (176.480 us; speedup 1.0000x reference)
//
#include <hip/hip_runtime.h>

#define B_    4
#define S_    128
#define BERT_ 768
#define C_    49
#define C1_   50
#define M_    288
#define HP_   25
#define WP_   144
#define NOUT_ 300

typedef short bf16x8 __attribute__((ext_vector_type(8)));
typedef short short4v __attribute__((ext_vector_type(4)));
typedef float f32x4 __attribute__((ext_vector_type(4)));

static __device__ __forceinline__ short f2bf(float f) {
  unsigned u = __float_as_uint(f);
  unsigned r = (u + 0x7fffu + ((u >> 16) & 1u)) >> 16;
  return (short)r;
}
static __device__ __forceinline__ float bf2f(short v) {
  return __uint_as_float(((unsigned)(unsigned short)v) << 16);
}
static __device__ __forceinline__ unsigned cvt_pk_bf16(float lo, float hi) {
  unsigned r;
  asm("v_cvt_pk_bf16_f32 %0, %1, %2" : "=v"(r) : "v"(lo), "v"(hi));
  return r;
}

// ------------------------------------------------------------------
// fused prep: casts, wperms, wsum, workspace zeroing
// ------------------------------------------------------------------
static __device__ __forceinline__ void cast_body(const float* src, short* dst,
                                                 long loOff, int R, int Ks, int Kd, int idx)
{
  if (idx >= R * Kd) return;
  int k = idx % Kd, r = idx / Kd;
  short h = 0, l = 0;
  if (k < Ks) {
    float v = src[(long)r * Ks + k];
    h = f2bf(v);
    l = f2bf(v - bf2f(h));
  }
  dst[idx] = h;
  dst[idx + loOff] = l;
}
static __device__ __forceinline__ void wperm_body(const float* w, short* wq, int r)
{
  if (r >= 128 * 128) return;
  int o = r >> 7, ch = r & 127;
  int chq = ch >> 3, e = ch & 7;
  const float* src = &w[(long)r * 25];
#pragma unroll
  for (int tap = 0; tap < 25; ++tap)
    wq[(((long)(tap * 16 + chq)) * 128 + o) * 8 + e] = f2bf(src[tap]);
}
__global__ __launch_bounds__(256) void prep_kernel(
    const float* __restrict__ bert, short* __restrict__ bertb,
    const float* __restrict__ W1, short* __restrict__ w1b,
    const float* __restrict__ Wo, short* __restrict__ wob,
    const float* __restrict__ c1w, short* __restrict__ w1p,
    const float* __restrict__ c2w, short* __restrict__ w2p,
    const float* __restrict__ w1m, const float* __restrict__ w2m,
    float* __restrict__ w1s, float* __restrict__ w2s,
    int4* __restrict__ zeroA, int4* __restrict__ zeroB)
{
  const int g = blockIdx.x, tid = threadIdx.x;
  if (g < 1536)       cast_body(bert, bertb, 393216L, 512, 768, 768, g * 256 + tid);
  else if (g < 2400)  cast_body(W1, w1b, 221184L, 288, 768, 768, (g - 1536) * 256 + tid);
  else if (g < 2700)  cast_body(Wo, wob, 76800L, 300, 144, 256, (g - 2400) * 256 + tid);
  else if (g < 2764)  wperm_body(c1w, w1p, (g - 2700) * 256 + tid);
  else if (g < 2828)  wperm_body(c2w, w2p, (g - 2764) * 256 + tid);
  else if (g < 2830) {
    int m = (g - 2828) * 256 + tid;
    if (m < M_) {
      float a = 0.f, b = 0.f;
      for (int c = 0; c < C1_; ++c) { a += w1m[m * C1_ + c]; b += w2m[m * C1_ + c]; }
      w1s[m] = a; w2s[m] = b;
    }
  } else if (g < 4132) {
    long idx = (long)(g - 2830) * 256 + tid;
    if (idx < 333056) zeroA[idx] = make_int4(0, 0, 0, 0);
  } else {
    long idx = (long)(g - 4132) * 256 + tid;
    if (idx < 159744) zeroB[idx] = make_int4(0, 0, 0, 0);
  }
}

// ------------------------------------------------------------------
// split-bf16 MFMA GEMM. Out[i,j] = sum_k A[i,k]*B[j,k] (+bias)
// ------------------------------------------------------------------
template<int OMODE>
__global__ __launch_bounds__(256) void gemm_split(
    const short* __restrict__ A, const short* __restrict__ Bm,
    const float* __restrict__ bias,
    float* __restrict__ Outf, short* __restrict__ Outb,
    int Mr, int Nc, int KH,
    long aB, int aP, long aLo,
    long bB, int bP, long bLo,
    long oB, int oP,
    long obB, int obP, long obLo,
    const int* __restrict__ ml, const int* __restrict__ ign)
{
  const int z = blockIdx.z;
  const int i0 = blockIdx.y * 64, j0 = blockIdx.x * 64;
  __shared__ __attribute__((aligned(16))) short As[2][64 * 64];
  __shared__ __attribute__((aligned(16))) short Bs[2][64 * 64];
  const int tid = threadIdx.x;
  const int wave = tid >> 6, lane = tid & 63;
  const int lr = lane & 15, kq = lane >> 4;
  f32x4 acc[4] = {};
  const short* Ab = A + z * aB;
  const short* Bb = Bm + z * bB;
  const bf16x8 vz = {0, 0, 0, 0, 0, 0, 0, 0};
  for (int kh = 0; kh < KH; ++kh) {
    if (kh) __syncthreads();
    for (int u = tid; u < 512; u += 256) {
      int row = u >> 3, c = u & 7;
      int gi = i0 + row;
      const short* src = &Ab[(long)gi * aP + kh * 64 + c * 8];
      bf16x8 vh = (gi < Mr) ? *(const bf16x8*)src : vz;
      bf16x8 vl = (gi < Mr) ? *(const bf16x8*)(src + aLo) : vz;
      int dst = row * 64 + ((c ^ (row & 7)) * 8);
      *(bf16x8*)&As[0][dst] = vh;
      *(bf16x8*)&As[1][dst] = vl;
    }
    for (int u = tid; u < 512; u += 256) {
      int row = u >> 3, c = u & 7;
      int gj = j0 + row;
      const short* src = &Bb[(long)gj * bP + kh * 64 + c * 8];
      bf16x8 vh = (gj < Nc) ? *(const bf16x8*)src : vz;
      bf16x8 vl = (gj < Nc) ? *(const bf16x8*)(src + bLo) : vz;
      int dst = row * 64 + ((c ^ (row & 7)) * 8);
      *(bf16x8*)&Bs[0][dst] = vh;
      *(bf16x8*)&Bs[1][dst] = vl;
    }
    __syncthreads();
#pragma unroll
    for (int ks = 0; ks < 2; ++ks) {
      const int ch = ks * 4 + kq;
      const int ar = wave * 16 + lr;
      const int ao = ar * 64 + ((ch ^ (ar & 7)) * 8);
      bf16x8 ah = *(const bf16x8*)&As[0][ao];
      bf16x8 al = *(const bf16x8*)&As[1][ao];
#pragma unroll
      for (int ni = 0; ni < 4; ++ni) {
        const int br = ni * 16 + lr;
        const int bo2 = br * 64 + ((ch ^ (br & 7)) * 8);
        bf16x8 bh = *(const bf16x8*)&Bs[0][bo2];
        bf16x8 bl = *(const bf16x8*)&Bs[1][bo2];
        acc[ni] = __builtin_amdgcn_mfma_f32_16x16x32_bf16(ah, bh, acc[ni], 0, 0, 0);
        acc[ni] = __builtin_amdgcn_mfma_f32_16x16x32_bf16(ah, bl, acc[ni], 0, 0, 0);
        acc[ni] = __builtin_amdgcn_mfma_f32_16x16x32_bf16(al, bh, acc[ni], 0, 0, 0);
      }
    }
  }
#pragma unroll
  for (int ni = 0; ni < 4; ++ni) {
    int jg = j0 + ni * 16 + lr;
    if (jg >= Nc) continue;
#pragma unroll
    for (int r = 0; r < 4; ++r) {
      int ig = i0 + wave * 16 + kq * 4 + r;
      if (ig >= Mr) continue;
      float v = acc[ni][r];
      if (bias) v += bias[jg];
      if constexpr (OMODE == 0)
        Outf[z * oB + (long)ig * oP + jg] = v;
      if constexpr (OMODE == 1) {
        long o = ((long)((ig >> 7) * 288 + jg)) * 128 + (ig & 127);
        short h = f2bf(v);
        Outb[o] = h;
        Outb[o + obLo] = f2bf(v - bf2f(h));
      }
      if constexpr (OMODE == 2) {
        long o = z * obB + (long)ig * obP + jg;
        short h = f2bf(v);
        Outb[o] = h;
        Outb[o + obLo] = f2bf(v - bf2f(h));
      }
      if constexpr (OMODE == 3) {
        if (ign[0] != 0 && ml[ig] <= 0) v = 0.f;
        Outf[z * oB + (long)ig * oP + jg] = v;
      }
    }
  }
}

// ------------------------------------------------------------------
// ebbar v3: reads split ebt[b][m][s] (s-contiguous). grid 5 x 256.
// ------------------------------------------------------------------
__global__ __launch_bounds__(256) void ebbar_kernel(
    const short* __restrict__ ebt, float* __restrict__ ebb)
{
  int row = blockIdx.x * 256 + threadIdx.x;      // b*288 + m
  if (row >= 4 * M_) return;
  const short* hi = &ebt[(long)row * 128];
  const short* lo = hi + 147456;
  float s = 0.f;
#pragma unroll
  for (int q = 0; q < 16; ++q) {
    bf16x8 vh = *(const bf16x8*)&hi[q * 8];
    bf16x8 vl = *(const bf16x8*)&lo[q * 8];
#pragma unroll
    for (int e = 0; e < 8; ++e) s += bf2f(vh[e]) + bf2f(vl[e]);
  }
  ebb[row] = s * (1.f / (float)S_);
}

// ------------------------------------------------------------------
// FUSED score + P-Gram GEMM (independent work, one launch, 256 threads).
// ------------------------------------------------------------------
__global__ __launch_bounds__(256) void score_p_kernel(
    const float* __restrict__ mem, const float* __restrict__ sentinel,
    const float* __restrict__ ebbar, const float* __restrict__ cw,
    const int* __restrict__ ml, float* __restrict__ E, short* __restrict__ Eb,
    float* __restrict__ attTp,
    const short* __restrict__ ebt, short* __restrict__ pb)
{
  __shared__ float sEb[M_];
  __shared__ float sE[4][M_];
  __shared__ float sScore[C1_];
  __shared__ __attribute__((aligned(16))) short As[2][64 * 64];
  __shared__ __attribute__((aligned(16))) short Bs[2][64 * 64];
  const int gb = blockIdx.x;
  const int tid = threadIdx.x, wave = tid >> 6, lane = tid & 63;

  if (gb < 512) {
    const int s = gb & 127, b = gb >> 7;
    for (int m = tid; m < M_; m += 256) sEb[m] = ebbar[b * M_ + m];
    __syncthreads();

    const float* base = mem + ((long)(b * S_ + s)) * C_ * M_;
    float Ereg[5] = {0.f, 0.f, 0.f, 0.f, 0.f};
    for (int jj = wave; jj < C_; jj += 4) {
      const float* row = base + (long)jj * M_;
      float d = 0.f;
#pragma unroll
      for (int q = 0; q < 5; ++q) {
        int m = lane + q * 64;
        if (m < M_) { float v = row[m]; Ereg[q] += v; d = fmaf(v, sEb[m], d); }
      }
#pragma unroll
      for (int off = 32; off; off >>= 1) d += __shfl_down(d, off, 64);
      if (lane == 0) sScore[jj + 1] = d;
    }
#pragma unroll
    for (int q = 0; q < 5; ++q) { int m = lane + q * 64; if (m < M_) sE[wave][m] = Ereg[q]; }
    __syncthreads();

    if (wave == 0) {
      float d0 = 0.f;
      for (int m = lane; m < M_; m += 64) d0 = fmaf(sentinel[m], sEb[m], d0);
#pragma unroll
      for (int off = 32; off; off >>= 1) d0 += __shfl_down(d0, off, 64);
      if (lane == 0) sScore[0] = d0;
    }
    for (int m = tid; m < M_; m += 256) {
      float ev = sentinel[m] + sE[0][m] + sE[1][m] + sE[2][m] + sE[3][m];
      E[((long)(b * S_ + s)) * M_ + m] = ev;
      short h = f2bf(ev);
      Eb[((long)(b * S_ + s)) * 384 + m] = h;
      Eb[196608 + ((long)(b * S_ + s)) * 384 + m] = f2bf(ev - bf2f(h));
    }
    __syncthreads();

    if (wave == 0) {
      const int mlv = ml[b * S_ + s];
      float sc = (lane < C1_) ? sScore[lane] : 0.f;
      if (lane < C1_ && mlv < lane) sc -= 1e6f;
      float mx = (lane < C1_) ? sc : -3.0e38f;
#pragma unroll
      for (int off = 32; off; off >>= 1) mx = fmaxf(mx, __shfl_xor(mx, off, 64));
      float e1 = (lane < C1_) ? __expf(sc - mx) : 0.f;
      float s1 = e1;
#pragma unroll
      for (int off = 32; off; off >>= 1) s1 += __shfl_xor(s1, off, 64);
      float p1 = e1 / s1;
      float cv = 0.f;
      if (lane >= 1 && lane < C1_) cv = cw[((long)(b * S_ + s)) * C_ + lane - 1];
      float mx2 = (lane < C1_) ? cv : -3.0e38f;
#pragma unroll
      for (int off = 32; off; off >>= 1) mx2 = fmaxf(mx2, __shfl_xor(mx2, off, 64));
      float e2 = (lane < C1_) ? __expf(cv - mx2) : 0.f;
      float s2 = e2;
#pragma unroll
      for (int off = 32; off; off >>= 1) s2 += __shfl_xor(s2, off, 64);
      float p2 = e2 / s2;
      float scm = 0.7f * p1 + 0.3f * p2;
      bool active = (lane < C1_);
      float thr = 0.f;
      for (int r = 0; r < 5; ++r) {
        float v = active ? scm : -3.0e38f;
        int idx = lane;
#pragma unroll
        for (int off = 32; off; off >>= 1) {
          float ov = __shfl_xor(v, off, 64);
          int oi = __shfl_xor(idx, off, 64);
          if (ov > v || (ov == v && oi < idx)) { v = ov; idx = oi; }
        }
        thr = v;
        if (lane == idx) active = false;
      }
      float kept = (lane < C1_ && scm >= thr) ? scm : 0.f;
      float mx3 = (lane < C1_) ? kept : -3.0e38f;
#pragma unroll
      for (int off = 32; off; off >>= 1) mx3 = fmaxf(mx3, __shfl_xor(mx3, off, 64));
      float e3 = (lane < C1_) ? __expf(kept - mx3) : 0.f;
      float s3 = e3;
#pragma unroll
      for (int off = 32; off; off >>= 1) s3 += __shfl_xor(s3, off, 64);
      if (lane < C1_) attTp[((long)(b * 54) + lane + 2) * 128 + s] = e3 / s3;
    }
  } else {
    // ---- P body: pb_z = ebt_z @ ebt_z^T, split out, bounds-guarded
    const int j = gb - 512;
    const int z = j / 25, rem = j % 25;
    const int i0 = (rem / 5) * 64, j0 = (rem % 5) * 64;
    const int lr = lane & 15, kq = lane >> 4;
    const bf16x8 vz = {0, 0, 0, 0, 0, 0, 0, 0};
    f32x4 acc[4] = {};
    const short* Ab = ebt + (long)z * 36864;     // 288*128
    for (int kh = 0; kh < 2; ++kh) {
      if (kh) __syncthreads();
      for (int u = tid; u < 512; u += 256) {
        int row = u >> 3, c = u & 7;
        int gi = i0 + row;
        bf16x8 vh = vz, vl = vz;
        if (gi < M_) {
          const short* src = &Ab[(long)gi * 128 + kh * 64 + c * 8];
          vh = *(const bf16x8*)src;
          vl = *(const bf16x8*)(src + 147456);
        }
        int dst = row * 64 + ((c ^ (row & 7)) * 8);
        *(bf16x8*)&As[0][dst] = vh;
        *(bf16x8*)&As[1][dst] = vl;
      }
      for (int u = tid; u < 512; u += 256) {
        int row = u >> 3, c = u & 7;
        int gj = j0 + row;
        bf16x8 vh = vz, vl = vz;
        if (gj < M_) {
          const short* src = &Ab[(long)gj * 128 + kh * 64 + c * 8];
          vh = *(const bf16x8*)src;
          vl = *(const bf16x8*)(src + 147456);
        }
        int dst = row * 64 + ((c ^ (row & 7)) * 8);
        *(bf16x8*)&Bs[0][dst] = vh;
        *(bf16x8*)&Bs[1][dst] = vl;
      }
      __syncthreads();
#pragma unroll
      for (int ks = 0; ks < 2; ++ks) {
        const int ch = ks * 4 + kq;
        const int ar = wave * 16 + lr;
        const int ao = ar * 64 + ((ch ^ (ar & 7)) * 8);
        bf16x8 ah = *(const bf16x8*)&As[0][ao];
        bf16x8 al = *(const bf16x8*)&As[1][ao];
#pragma unroll
        for (int ni = 0; ni < 4; ++ni) {
          const int br = ni * 16 + lr;
          const int bo2 = br * 64 + ((ch ^ (br & 7)) * 8);
          bf16x8 bh = *(const bf16x8*)&Bs[0][bo2];
          bf16x8 bl = *(const bf16x8*)&Bs[1][bo2];
          acc[ni] = __builtin_amdgcn_mfma_f32_16x16x32_bf16(ah, bh, acc[ni], 0, 0, 0);
          acc[ni] = __builtin_amdgcn_mfma_f32_16x16x32_bf16(ah, bl, acc[ni], 0, 0, 0);
          acc[ni] = __builtin_amdgcn_mfma_f32_16x16x32_bf16(al, bh, acc[ni], 0, 0, 0);
        }
      }
    }
#pragma unroll
    for (int ni = 0; ni < 4; ++ni) {
      int jg = j0 + ni * 16 + lr;
      if (jg >= M_) continue;
#pragma unroll
      for (int r = 0; r < 4; ++r) {
        int ig = i0 + wave * 16 + kq * 4 + r;
        if (ig >= M_) continue;
        long o = (long)z * 110592 + (long)ig * 384 + jg;   // 288*384
        float v = acc[ni][r];
        short h = f2bf(v);
        pb[o] = h;
        pb[o + 442368] = f2bf(v - bf2f(h));
      }
    }
  }
}

// ------------------------------------------------------------------
// FUSED g_kernel + conv1_aw. g inner loop: 2 trans ops (exp, rcp);
// e^tanh via degree-7 Taylor on th in (-1,1) — rel err <= e/8! ~ 7e-5,
// 50x below G's bf16 rounding.
// ------------------------------------------------------------------
__global__ __launch_bounds__(576) void g_aw_kernel(
    const float* __restrict__ E, const float* __restrict__ t2,
    const float* __restrict__ w1s, const float* __restrict__ w2s,
    short* __restrict__ Gt,
    const short* __restrict__ w1q, const float* __restrict__ attp,
    short* __restrict__ AWq)
{
  __shared__ float sE[M_], s1[M_], s2[M_];
  __shared__ float sAtt[5][128];
  const int gb = blockIdx.x;
  const int tid = threadIdx.x;

  if (gb < 512) {
    const int s = gb & 127, b = gb >> 7;
    const long base = (long)(b * S_ + s) * M_;
    for (int m = tid; m < M_; m += 576) { sE[m] = E[base + m]; s1[m] = w1s[m]; s2[m] = w2s[m]; }
    __syncthreads();
    const int n = tid >> 1, half = tid & 1;
    const float a = sE[n];
    const float c = t2[base + n];
    float num = 0.f, den = 0.f;
    const int m0 = half * 144;
#pragma unroll 4
    for (int mm = 0; mm < 144; ++mm) {
      int m = m0 + mm;
      float z = fmaf(s1[m], a, s2[m] * c);
      float u = __expf(2.f * z);                               // trans 1
      float th = fmaf(-2.f, __builtin_amdgcn_rcpf(u + 1.f), 1.f);  // trans 2
      // e^th, th in (-1,1): degree-7 Taylor (Horner on VALU pipe)
      float p = 1.9841270e-4f;                   // 1/5040
      p = fmaf(p, th, 1.3888889e-3f);            // 1/720
      p = fmaf(p, th, 8.3333333e-3f);            // 1/120
      p = fmaf(p, th, 4.1666667e-2f);            // 1/24
      p = fmaf(p, th, 1.6666667e-1f);            // 1/6
      p = fmaf(p, th, 0.5f);
      p = fmaf(p, th, 1.0f);
      float e = fmaf(p, th, 1.0f);
      num = fmaf(sE[m], e, num);
      den += e;
    }
    num += __shfl_xor(num, 1, 64);
    den += __shfl_xor(den, 1, 64);
    if (half == 0)
      Gt[((long)(b * 292) + 2 + n) * 128 + s] = f2bf(num / den);
  } else {
    const int j = gb - 512;
    const int half = j & 1;
    const int h = (j >> 1) % 50;
    const int b = (j >> 1) / 50;
    if (tid < 256) {
      for (int u = tid; u < 640; u += 256)
        sAtt[u >> 7][u & 127] = attp[((long)(b * 54) + h + (u >> 7)) * 128 + (u & 127)];
    }
    __syncthreads();
    if (tid < 256) {
      const long obase = ((long)(b * 50 + h) * 80) * 1024;
      for (int u = tid; u < 5120; u += 256) {
        int c = half * 40 + (u >> 7);
        int o = u & 127;
        int dw = c / 16, chq = c & 15;
        float acc[8] = {};
#pragma unroll
        for (int dh = 0; dh < 5; ++dh) {
          bf16x8 wv = *(const bf16x8*)&w1q[(((long)((dh * 5 + dw) * 16 + chq)) * 128 + o) * 8];
          const float* ar = &sAtt[dh][chq * 8];
#pragma unroll
          for (int e = 0; e < 8; ++e) acc[e] = fmaf(bf2f(wv[e]), ar[e], acc[e]);
        }
        union { unsigned u4[4]; bf16x8 v; } pk;
        pk.u4[0] = cvt_pk_bf16(acc[0], acc[1]);
        pk.u4[1] = cvt_pk_bf16(acc[2], acc[3]);
        pk.u4[2] = cvt_pk_bf16(acc[4], acc[5]);
        pk.u4[3] = cvt_pk_bf16(acc[6], acc[7]);
        *(bf16x8*)&AWq[obase + (long)c * 1024 + o * 8] = pk.v;
      }
    }
  }
}

// ------------------------------------------------------------------
// conv1 stage B: per (b,h) GEMM over K=640 (dw,i). BM=128, BN=144.
// ------------------------------------------------------------------
__global__ __launch_bounds__(256) void conv1_mfma(
    const short* __restrict__ AWq, const short* __restrict__ Gt,
    const float* __restrict__ bias, short* __restrict__ y1t)
{
  const int b = blockIdx.z, hrow = blockIdx.y;
  const int w0 = blockIdx.x * 144;
  __shared__ __attribute__((aligned(16))) short Bs[2][148 * 64];
  const int tid = threadIdx.x;
  const int wave = tid >> 6, lane = tid & 63;
  const int lr = lane & 15, kq = lane >> 4;
  f32x4 acc[2][9] = {};

  const short* src = Gt + ((long)(b * 292) + w0) * 128;
  for (int u = tid; u < 2368; u += 256) {
    int row = u >> 4, c = u & 15;
    bf16x8 v = *(const bf16x8*)&src[row * 128 + c * 8];
    *(bf16x8*)&Bs[c >> 3][row * 64 + (((c & 7) ^ (row & 7)) * 8)] = v;
  }
  __syncthreads();

  const long awb = (long)(b * 50 + hrow) * 80;
  for (int dw = 0; dw < 5; ++dw) {
#pragma unroll
    for (int ks = 0; ks < 4; ++ks) {
      const int ch = ks * 4 + kq;
      const long abase = (awb + dw * 16 + ch) * 128 + wave * 32 + lr;
      bf16x8 af0 = *(const bf16x8*)&AWq[abase * 8];
      bf16x8 af1 = *(const bf16x8*)&AWq[(abase + 16) * 8];
      const int arr = ch >> 3, cc = ch & 7;
#pragma unroll
      for (int ni = 0; ni < 9; ++ni) {
        const int row = lr + ni * 16 + dw;
        bf16x8 bfr = *(const bf16x8*)&Bs[arr][row * 64 + ((cc ^ (row & 7)) * 8)];
        acc[0][ni] = __builtin_amdgcn_mfma_f32_16x16x32_bf16(af0, bfr, acc[0][ni], 0, 0, 0);
        acc[1][ni] = __builtin_amdgcn_mfma_f32_16x16x32_bf16(af1, bfr, acc[1][ni], 0, 0, 0);
      }
    }
  }
#pragma unroll
  for (int mi = 0; mi < 2; ++mi) {
    const int og = wave * 32 + mi * 16 + kq * 4;
#pragma unroll
    for (int ni = 0; ni < 9; ++ni) {
      int wg = w0 + ni * 16 + lr;
      short4v pk;
#pragma unroll
      for (int r = 0; r < 4; ++r)
        pk[r] = f2bf(fmaxf(acc[mi][ni][r] + bias[og + r], 0.f));
      *(short4v*)&y1t[(((long)(b * 50) + hrow) * 288 + wg) * 128 + og] = pk;
    }
  }
}

// ------------------------------------------------------------------
// conv2 v5: split-K over dh, pool fused into staging (reads y1t directly).
// ------------------------------------------------------------------
__global__ __launch_bounds__(256) void conv2_dh(
    const short* __restrict__ wq,
    const short* __restrict__ y1t,
    short* __restrict__ y2p)
{
  constexpr int NREP = 3;
  const int bz = blockIdx.z;            // b*5 + dh
  const int b = bz / 5, dh = bz % 5;
  const int hp = blockIdx.y;
  const int w0 = blockIdx.x * 48;
  __shared__ __attribute__((aligned(16))) short Bs[2][52 * 64];
  const int tid = threadIdx.x;
  const int wave = tid >> 6, lane = tid & 63;
  const int lr = lane & 15, kq = lane >> 4;
  const bf16x8 vz = {0, 0, 0, 0, 0, 0, 0, 0};
  f32x4 acc[2][NREP] = {};

  const int rr = hp + dh - 2;           // pooled row index (may be OOB)
  for (int u = tid; u < 832; u += 256) {
    int row = u >> 4, c = u & 15;
    int wp = w0 + row - 2;              // pooled col index (may be OOB)
    bf16x8 v = vz;
    if (rr >= 0 && rr < HP_ && wp >= 0 && wp < WP_) {
      const short* pbase = y1t + (((long)(b * 50 + 2 * rr) * 288) + 2 * wp) * 128 + c * 8;
      bf16x8 v00 = *(const bf16x8*)&pbase[0];
      bf16x8 v01 = *(const bf16x8*)&pbase[128];
      bf16x8 v10 = *(const bf16x8*)&pbase[288 * 128];
      bf16x8 v11 = *(const bf16x8*)&pbase[288 * 128 + 128];
#pragma unroll
      for (int e = 0; e < 8; ++e)
        v[e] = f2bf(fmaxf(fmaxf(bf2f(v00[e]), bf2f(v01[e])),
                          fmaxf(bf2f(v10[e]), bf2f(v11[e]))));
    }
    *(bf16x8*)&Bs[c >> 3][row * 64 + (((c & 7) ^ (row & 7)) * 8)] = v;
  }
  __syncthreads();

#pragma unroll
  for (int dw = 0; dw < 5; ++dw) {
    const int tap = dh * 5 + dw;
#pragma unroll
    for (int ks = 0; ks < 4; ++ks) {
      const int ch = ks * 4 + kq;
      const long abase = ((long)(tap * 16 + ch)) * 128 + wave * 32 + lr;
      bf16x8 af0 = *(const bf16x8*)&wq[abase * 8];
      bf16x8 af1 = *(const bf16x8*)&wq[(abase + 16) * 8];
      const int arr = ch >> 3, cc = ch & 7;
#pragma unroll
      for (int ni = 0; ni < NREP; ++ni) {
        const int row = lr + ni * 16 + dw;
        bf16x8 bfr = *(const bf16x8*)&Bs[arr][row * 64 + ((cc ^ (row & 7)) * 8)];
        acc[0][ni] = __builtin_amdgcn_mfma_f32_16x16x32_bf16(af0, bfr, acc[0][ni], 0, 0, 0);
        acc[1][ni] = __builtin_amdgcn_mfma_f32_16x16x32_bf16(af1, bfr, acc[1][ni], 0, 0, 0);
      }
    }
  }
#pragma unroll
  for (int mi = 0; mi < 2; ++mi) {
    const int og = wave * 32 + mi * 16 + kq * 4;
#pragma unroll
    for (int ni = 0; ni < NREP; ++ni) {
      int wg = w0 + ni * 16 + lr;
#pragma unroll
      for (int r = 0; r < 4; ++r)
        y2p[((long)(dh * 512 + b * 128 + og + r)) * 3600 + hp * 144 + wg] =
            f2bf(acc[mi][ni][r]);
    }
  }
}

// ------------------------------------------------------------------
// tail_fuse: per (b,o): sum partials + bias + relu -> LN(144) -> mean over hp
// ------------------------------------------------------------------
__global__ __launch_bounds__(256) void tail_fuse(
    const short* __restrict__ y2p, const float* __restrict__ bias,
    const float* __restrict__ lng, const float* __restrict__ lnb,
    short* __restrict__ zb)
{
  const int o = blockIdx.x, b = blockIdx.y;
  const int tid = threadIdx.x, wave = tid >> 6, lane = tid & 63;
  __shared__ float sZ[4][3][64];
  float zacc[3] = {0.f, 0.f, 0.f};
  const float bo = bias[o];
  const long base = ((long)(b * 128 + o)) * 3600;
  for (int hp = wave; hp < HP_; hp += 4) {
    float v[3]; float s = 0.f, ss = 0.f;
#pragma unroll
    for (int q = 0; q < 3; ++q) {
      int wp = lane + q * 64;
      float x = 0.f;
      if (wp < WP_) {
        x = bo;
#pragma unroll
        for (int dh = 0; dh < 5; ++dh)
          x += bf2f(y2p[(long)dh * 512 * 3600 + base + hp * 144 + wp]);
        x = fmaxf(x, 0.f);
      }
      v[q] = x; s += x; ss = fmaf(x, x, ss);
    }
#pragma unroll
    for (int off = 32; off; off >>= 1) { s += __shfl_xor(s, off, 64); ss += __shfl_xor(ss, off, 64); }
    float mu = s * (1.f / (float)WP_);
    float var = ss * (1.f / (float)WP_) - mu * mu;
    float inv = rsqrtf(var + 1e-5f);
#pragma unroll
    for (int q = 0; q < 3; ++q) {
      int wp = lane + q * 64;
      if (wp < WP_) zacc[q] += (v[q] - mu) * inv * lng[wp] + lnb[wp];
    }
  }
#pragma unroll
  for (int q = 0; q < 3; ++q) sZ[wave][q][lane] = zacc[q];
  __syncthreads();
  if (wave == 0) {
#pragma unroll
    for (int q = 0; q < 3; ++q) {
      int wp = lane + q * 64;
      if (wp < WP_) {
        float z = (sZ[0][q][lane] + sZ[1][q][lane] + sZ[2][q][lane] + sZ[3][q][lane])
                  * (1.f / (float)HP_);
        long t = (long)(b * 128 + o);
        short h = f2bf(z);
        zb[t * 256 + wp] = h;
        zb[131072 + t * 256 + wp] = f2bf(z - bf2f(h));
      }
    }
  }
}

// ------------------------------------------------------------------
extern "C" void kernel_launch(void* const* d_in, const int* in_sizes, int n_in,
                              void* d_out, int out_size, void* d_ws, size_t ws_size,
                              hipStream_t stream)
{
  const float* bert = (const float*)d_in[0];
  const float* mem  = (const float*)d_in[1];
  const int*   ml   = (const int*)d_in[2];
  const float* cw   = (const float*)d_in[3];
  const int*   ign  = (const int*)d_in[4];
  const float* W1   = (const float*)d_in[6];
  const float* b1l  = (const float*)d_in[7];
  const float* sent = (const float*)d_in[8];
  const float* w1m  = (const float*)d_in[9];
  const float* w2m  = (const float*)d_in[10];
  const float* c1w  = (const float*)d_in[11];
  const float* c1b  = (const float*)d_in[12];
  const float* c2w  = (const float*)d_in[13];
  const float* c2b  = (const float*)d_in[14];
  const float* lng  = (const float*)d_in[15];
  const float* lnb  = (const float*)d_in[16];
  const float* Wo   = (const float*)d_in[17];
  const float* bo   = (const float*)d_in[18];
  float* out = (float*)d_out;

  // ---- A-region (persistent) ----
  short* Gt    = (short*)d_ws;             // 149504
  short* x2t   = Gt + 149504;              // 2197504 (dead buffer, kept for layout)
  short* zb    = x2t + 2197504;            // 262144
  float* attTp = (float*)(zb + 262144);    // 27648 f32
  float* w1s   = attTp + 27648;            // 288
  float* w2s   = w1s + 288;                // 288
  float* ebb   = w2s + 288;                // 1152
  short* wob   = (short*)(ebb + 1152);     // 153600
  short* w1p   = wob + 153600;             // 409600
  short* w2p   = w1p + 409600;             // 409600
  short* y1t   = w2p + 409600;             // 7372800
  // ---- pool X, lifetime-disjoint phases ----
  short* poolX = y1t + 7372800;
  short* bertb = poolX;                    // 786432 (hi+lo)
  short* w1b   = bertb + 786432;           // 442368
  short* ebt   = w1b + 442368;             // 294912 (hi+lo)
  short* Eb    = ebt + 294912;             // 393216
  short* pb    = Eb + 393216;              // 884736
  float* E     = (float*)(pb + 884736);    // 147456 f32
  float* t2    = E + 147456;               // 147456
  short* AWq   = poolX;                    // phase 2 (conv1): 16384000 shorts
  short* y2p   = poolX;                    // phase 3 (conv2 partials): 9216000 shorts

  dim3 blk(256);

  // fused prep: casts + wperms + wsum + in-kernel zeroing
  prep_kernel<<<dim3(4756), blk, 0, stream>>>(
      bert, bertb, W1, w1b, Wo, wob, c1w, w1p, c2w, w2p, w1m, w2m, w1s, w2s,
      (int4*)d_ws, (int4*)Eb);

  // eb = bert @ W1^T + b1  [512x288] K=768; split ebt only
  gemm_split<1><<<dim3(5, 8, 1), blk, 0, stream>>>(
      bertb, w1b, b1l, (float*)nullptr, ebt, 512, 288, 12,
      0L, 768, 393216L, 0L, 768, 221184L, 0L, 288, 0L, 0, 147456L,
      (const int*)nullptr, (const int*)nullptr);

  // ebbar v3: reads s-contiguous split ebt
  ebbar_kernel<<<dim3(5), blk, 0, stream>>>(ebt, ebb);

  // fused score + P-Gram GEMM: 512 score-blocks + 100 P-blocks
  score_p_kernel<<<dim3(612), blk, 0, stream>>>(
      mem, sent, ebb, cw, ml, E, Eb, attTp, ebt, pb);

  // t2 = E @ P  [128x288] K=384(pad)
  gemm_split<0><<<dim3(5, 2, 4), blk, 0, stream>>>(
      Eb, pb, (const float*)nullptr, t2, (short*)nullptr, 128, 288, 6,
      (long)128 * 384, 384, 196608L, (long)288 * 384, 384, 442368L,
      (long)128 * 288, 288, 0L, 0, 0L,
      (const int*)nullptr, (const int*)nullptr);

  // fused g_kernel + conv1_aw: 512 g-blocks + 400 aw-blocks, 576 threads
  g_aw_kernel<<<dim3(912), dim3(576), 0, stream>>>(
      E, t2, w1s, w2s, Gt, w1p, attTp, AWq);

  conv1_mfma<<<dim3(2, 50, 4), blk, 0, stream>>>(AWq, Gt, c1b, y1t);

  // conv2 with fused pooling (reads y1t directly)
  conv2_dh<<<dim3(3, 25, 20), blk, 0, stream>>>(w2p, y1t, y2p);

  // fused: reduce + bias + relu + LN + mean_hp -> zb
  tail_fuse<<<dim3(128, 4), blk, 0, stream>>>(y2p, c2b, lng, lnb, zb);

  // out = z @ W_out^T + b_out, masked  [512x300] K=256(pad)
  gemm_split<3><<<dim3(5, 8, 1), blk, 0, stream>>>(
      zb, wob, bo, out, (short*)nullptr, 512, 300, 4,
      0L, 256, 131072L, 0L, 256, 76800L, 0L, 300, 0L, 0, 0L,
      ml, ign);
}

// Round 25
// 173.761 us; speedup vs baseline: 1.0157x; 1.0157x over previous
//
#include <hip/hip_runtime.h>

#define B_    4
#define S_    128
#define BERT_ 768
#define C_    49
#define C1_   50
#define M_    288
#define HP_   25
#define WP_   144
#define NOUT_ 300

typedef short bf16x8 __attribute__((ext_vector_type(8)));
typedef short short4v __attribute__((ext_vector_type(4)));
typedef float f32x4 __attribute__((ext_vector_type(4)));

static __device__ __forceinline__ short f2bf(float f) {
  unsigned u = __float_as_uint(f);
  unsigned r = (u + 0x7fffu + ((u >> 16) & 1u)) >> 16;
  return (short)r;
}
static __device__ __forceinline__ float bf2f(short v) {
  return __uint_as_float(((unsigned)(unsigned short)v) << 16);
}
static __device__ __forceinline__ unsigned cvt_pk_bf16(float lo, float hi) {
  unsigned r;
  asm("v_cvt_pk_bf16_f32 %0, %1, %2" : "=v"(r) : "v"(lo), "v"(hi));
  return r;
}

// ------------------------------------------------------------------
// fused prep: casts, wperms, wsum, workspace zeroing
// ------------------------------------------------------------------
static __device__ __forceinline__ void cast_body(const float* src, short* dst,
                                                 long loOff, int R, int Ks, int Kd, int idx)
{
  if (idx >= R * Kd) return;
  int k = idx % Kd, r = idx / Kd;
  short h = 0, l = 0;
  if (k < Ks) {
    float v = src[(long)r * Ks + k];
    h = f2bf(v);
    l = f2bf(v - bf2f(h));
  }
  dst[idx] = h;
  dst[idx + loOff] = l;
}
static __device__ __forceinline__ void wperm_body(const float* w, short* wq, int r)
{
  if (r >= 128 * 128) return;
  int o = r >> 7, ch = r & 127;
  int chq = ch >> 3, e = ch & 7;
  const float* src = &w[(long)r * 25];
#pragma unroll
  for (int tap = 0; tap < 25; ++tap)
    wq[(((long)(tap * 16 + chq)) * 128 + o) * 8 + e] = f2bf(src[tap]);
}
__global__ __launch_bounds__(256) void prep_kernel(
    const float* __restrict__ bert, short* __restrict__ bertb,
    const float* __restrict__ W1, short* __restrict__ w1b,
    const float* __restrict__ Wo, short* __restrict__ wob,
    const float* __restrict__ c1w, short* __restrict__ w1p,
    const float* __restrict__ c2w, short* __restrict__ w2p,
    const float* __restrict__ w1m, const float* __restrict__ w2m,
    float* __restrict__ w1s, float* __restrict__ w2s,
    int4* __restrict__ zeroA, int4* __restrict__ zeroB)
{
  const int g = blockIdx.x, tid = threadIdx.x;
  if (g < 1536)       cast_body(bert, bertb, 393216L, 512, 768, 768, g * 256 + tid);
  else if (g < 2400)  cast_body(W1, w1b, 221184L, 288, 768, 768, (g - 1536) * 256 + tid);
  else if (g < 2700)  cast_body(Wo, wob, 76800L, 300, 144, 256, (g - 2400) * 256 + tid);
  else if (g < 2764)  wperm_body(c1w, w1p, (g - 2700) * 256 + tid);
  else if (g < 2828)  wperm_body(c2w, w2p, (g - 2764) * 256 + tid);
  else if (g < 2830) {
    int m = (g - 2828) * 256 + tid;
    if (m < M_) {
      float a = 0.f, b = 0.f;
      for (int c = 0; c < C1_; ++c) { a += w1m[m * C1_ + c]; b += w2m[m * C1_ + c]; }
      w1s[m] = a; w2s[m] = b;
    }
  } else if (g < 4132) {
    long idx = (long)(g - 2830) * 256 + tid;
    if (idx < 333056) zeroA[idx] = make_int4(0, 0, 0, 0);
  } else {
    long idx = (long)(g - 4132) * 256 + tid;
    if (idx < 159744) zeroB[idx] = make_int4(0, 0, 0, 0);
  }
}

// ------------------------------------------------------------------
// split-bf16 MFMA GEMM. Out[i,j] = sum_k A[i,k]*B[j,k] (+bias)
// ------------------------------------------------------------------
template<int OMODE>
__global__ __launch_bounds__(256) void gemm_split(
    const short* __restrict__ A, const short* __restrict__ Bm,
    const float* __restrict__ bias,
    float* __restrict__ Outf, short* __restrict__ Outb,
    int Mr, int Nc, int KH,
    long aB, int aP, long aLo,
    long bB, int bP, long bLo,
    long oB, int oP,
    long obB, int obP, long obLo,
    const int* __restrict__ ml, const int* __restrict__ ign)
{
  const int z = blockIdx.z;
  const int i0 = blockIdx.y * 64, j0 = blockIdx.x * 64;
  __shared__ __attribute__((aligned(16))) short As[2][64 * 64];
  __shared__ __attribute__((aligned(16))) short Bs[2][64 * 64];
  const int tid = threadIdx.x;
  const int wave = tid >> 6, lane = tid & 63;
  const int lr = lane & 15, kq = lane >> 4;
  f32x4 acc[4] = {};
  const short* Ab = A + z * aB;
  const short* Bb = Bm + z * bB;
  const bf16x8 vz = {0, 0, 0, 0, 0, 0, 0, 0};
  for (int kh = 0; kh < KH; ++kh) {
    if (kh) __syncthreads();
    for (int u = tid; u < 512; u += 256) {
      int row = u >> 3, c = u & 7;
      int gi = i0 + row;
      const short* src = &Ab[(long)gi * aP + kh * 64 + c * 8];
      bf16x8 vh = (gi < Mr) ? *(const bf16x8*)src : vz;
      bf16x8 vl = (gi < Mr) ? *(const bf16x8*)(src + aLo) : vz;
      int dst = row * 64 + ((c ^ (row & 7)) * 8);
      *(bf16x8*)&As[0][dst] = vh;
      *(bf16x8*)&As[1][dst] = vl;
    }
    for (int u = tid; u < 512; u += 256) {
      int row = u >> 3, c = u & 7;
      int gj = j0 + row;
      const short* src = &Bb[(long)gj * bP + kh * 64 + c * 8];
      bf16x8 vh = (gj < Nc) ? *(const bf16x8*)src : vz;
      bf16x8 vl = (gj < Nc) ? *(const bf16x8*)(src + bLo) : vz;
      int dst = row * 64 + ((c ^ (row & 7)) * 8);
      *(bf16x8*)&Bs[0][dst] = vh;
      *(bf16x8*)&Bs[1][dst] = vl;
    }
    __syncthreads();
#pragma unroll
    for (int ks = 0; ks < 2; ++ks) {
      const int ch = ks * 4 + kq;
      const int ar = wave * 16 + lr;
      const int ao = ar * 64 + ((ch ^ (ar & 7)) * 8);
      bf16x8 ah = *(const bf16x8*)&As[0][ao];
      bf16x8 al = *(const bf16x8*)&As[1][ao];
#pragma unroll
      for (int ni = 0; ni < 4; ++ni) {
        const int br = ni * 16 + lr;
        const int bo2 = br * 64 + ((ch ^ (br & 7)) * 8);
        bf16x8 bh = *(const bf16x8*)&Bs[0][bo2];
        bf16x8 bl = *(const bf16x8*)&Bs[1][bo2];
        acc[ni] = __builtin_amdgcn_mfma_f32_16x16x32_bf16(ah, bh, acc[ni], 0, 0, 0);
        acc[ni] = __builtin_amdgcn_mfma_f32_16x16x32_bf16(ah, bl, acc[ni], 0, 0, 0);
        acc[ni] = __builtin_amdgcn_mfma_f32_16x16x32_bf16(al, bh, acc[ni], 0, 0, 0);
      }
    }
  }
#pragma unroll
  for (int ni = 0; ni < 4; ++ni) {
    int jg = j0 + ni * 16 + lr;
    if (jg >= Nc) continue;
#pragma unroll
    for (int r = 0; r < 4; ++r) {
      int ig = i0 + wave * 16 + kq * 4 + r;
      if (ig >= Mr) continue;
      float v = acc[ni][r];
      if (bias) v += bias[jg];
      if constexpr (OMODE == 0)
        Outf[z * oB + (long)ig * oP + jg] = v;
      if constexpr (OMODE == 1) {
        long o = ((long)((ig >> 7) * 288 + jg)) * 128 + (ig & 127);
        short h = f2bf(v);
        Outb[o] = h;
        Outb[o + obLo] = f2bf(v - bf2f(h));
      }
      if constexpr (OMODE == 2) {
        long o = z * obB + (long)ig * obP + jg;
        short h = f2bf(v);
        Outb[o] = h;
        Outb[o + obLo] = f2bf(v - bf2f(h));
      }
      if constexpr (OMODE == 3) {
        if (ign[0] != 0 && ml[ig] <= 0) v = 0.f;
        Outf[z * oB + (long)ig * oP + jg] = v;
      }
    }
  }
}

// ------------------------------------------------------------------
// ebbar v3: reads split ebt[b][m][s] (s-contiguous). grid 5 x 256.
// ------------------------------------------------------------------
__global__ __launch_bounds__(256) void ebbar_kernel(
    const short* __restrict__ ebt, float* __restrict__ ebb)
{
  int row = blockIdx.x * 256 + threadIdx.x;      // b*288 + m
  if (row >= 4 * M_) return;
  const short* hi = &ebt[(long)row * 128];
  const short* lo = hi + 147456;
  float s = 0.f;
#pragma unroll
  for (int q = 0; q < 16; ++q) {
    bf16x8 vh = *(const bf16x8*)&hi[q * 8];
    bf16x8 vl = *(const bf16x8*)&lo[q * 8];
#pragma unroll
    for (int e = 0; e < 8; ++e) s += bf2f(vh[e]) + bf2f(vl[e]);
  }
  ebb[row] = s * (1.f / (float)S_);
}

// ------------------------------------------------------------------
// FUSED score + P-Gram GEMM (independent work, one launch, 256 threads).
// ------------------------------------------------------------------
__global__ __launch_bounds__(256) void score_p_kernel(
    const float* __restrict__ mem, const float* __restrict__ sentinel,
    const float* __restrict__ ebbar, const float* __restrict__ cw,
    const int* __restrict__ ml, float* __restrict__ E, short* __restrict__ Eb,
    float* __restrict__ attTp,
    const short* __restrict__ ebt, short* __restrict__ pb)
{
  __shared__ float sEb[M_];
  __shared__ float sE[4][M_];
  __shared__ float sScore[C1_];
  __shared__ __attribute__((aligned(16))) short As[2][64 * 64];
  __shared__ __attribute__((aligned(16))) short Bs[2][64 * 64];
  const int gb = blockIdx.x;
  const int tid = threadIdx.x, wave = tid >> 6, lane = tid & 63;

  if (gb < 512) {
    const int s = gb & 127, b = gb >> 7;
    for (int m = tid; m < M_; m += 256) sEb[m] = ebbar[b * M_ + m];
    __syncthreads();

    const float* base = mem + ((long)(b * S_ + s)) * C_ * M_;
    float Ereg[5] = {0.f, 0.f, 0.f, 0.f, 0.f};
    for (int jj = wave; jj < C_; jj += 4) {
      const float* row = base + (long)jj * M_;
      float d = 0.f;
#pragma unroll
      for (int q = 0; q < 5; ++q) {
        int m = lane + q * 64;
        if (m < M_) { float v = row[m]; Ereg[q] += v; d = fmaf(v, sEb[m], d); }
      }
#pragma unroll
      for (int off = 32; off; off >>= 1) d += __shfl_down(d, off, 64);
      if (lane == 0) sScore[jj + 1] = d;
    }
#pragma unroll
    for (int q = 0; q < 5; ++q) { int m = lane + q * 64; if (m < M_) sE[wave][m] = Ereg[q]; }
    __syncthreads();

    if (wave == 0) {
      float d0 = 0.f;
      for (int m = lane; m < M_; m += 64) d0 = fmaf(sentinel[m], sEb[m], d0);
#pragma unroll
      for (int off = 32; off; off >>= 1) d0 += __shfl_down(d0, off, 64);
      if (lane == 0) sScore[0] = d0;
    }
    for (int m = tid; m < M_; m += 256) {
      float ev = sentinel[m] + sE[0][m] + sE[1][m] + sE[2][m] + sE[3][m];
      E[((long)(b * S_ + s)) * M_ + m] = ev;
      short h = f2bf(ev);
      Eb[((long)(b * S_ + s)) * 384 + m] = h;
      Eb[196608 + ((long)(b * S_ + s)) * 384 + m] = f2bf(ev - bf2f(h));
    }
    __syncthreads();

    if (wave == 0) {
      const int mlv = ml[b * S_ + s];
      float sc = (lane < C1_) ? sScore[lane] : 0.f;
      if (lane < C1_ && mlv < lane) sc -= 1e6f;
      float mx = (lane < C1_) ? sc : -3.0e38f;
#pragma unroll
      for (int off = 32; off; off >>= 1) mx = fmaxf(mx, __shfl_xor(mx, off, 64));
      float e1 = (lane < C1_) ? __expf(sc - mx) : 0.f;
      float s1 = e1;
#pragma unroll
      for (int off = 32; off; off >>= 1) s1 += __shfl_xor(s1, off, 64);
      float p1 = e1 / s1;
      float cv = 0.f;
      if (lane >= 1 && lane < C1_) cv = cw[((long)(b * S_ + s)) * C_ + lane - 1];
      float mx2 = (lane < C1_) ? cv : -3.0e38f;
#pragma unroll
      for (int off = 32; off; off >>= 1) mx2 = fmaxf(mx2, __shfl_xor(mx2, off, 64));
      float e2 = (lane < C1_) ? __expf(cv - mx2) : 0.f;
      float s2 = e2;
#pragma unroll
      for (int off = 32; off; off >>= 1) s2 += __shfl_xor(s2, off, 64);
      float p2 = e2 / s2;
      float scm = 0.7f * p1 + 0.3f * p2;
      bool active = (lane < C1_);
      float thr = 0.f;
      for (int r = 0; r < 5; ++r) {
        float v = active ? scm : -3.0e38f;
        int idx = lane;
#pragma unroll
        for (int off = 32; off; off >>= 1) {
          float ov = __shfl_xor(v, off, 64);
          int oi = __shfl_xor(idx, off, 64);
          if (ov > v || (ov == v && oi < idx)) { v = ov; idx = oi; }
        }
        thr = v;
        if (lane == idx) active = false;
      }
      float kept = (lane < C1_ && scm >= thr) ? scm : 0.f;
      float mx3 = (lane < C1_) ? kept : -3.0e38f;
#pragma unroll
      for (int off = 32; off; off >>= 1) mx3 = fmaxf(mx3, __shfl_xor(mx3, off, 64));
      float e3 = (lane < C1_) ? __expf(kept - mx3) : 0.f;
      float s3 = e3;
#pragma unroll
      for (int off = 32; off; off >>= 1) s3 += __shfl_xor(s3, off, 64);
      if (lane < C1_) attTp[((long)(b * 54) + lane + 2) * 128 + s] = e3 / s3;
    }
  } else {
    // ---- P body: pb_z = ebt_z @ ebt_z^T, split out, bounds-guarded
    const int j = gb - 512;
    const int z = j / 25, rem = j % 25;
    const int i0 = (rem / 5) * 64, j0 = (rem % 5) * 64;
    const int lr = lane & 15, kq = lane >> 4;
    const bf16x8 vz = {0, 0, 0, 0, 0, 0, 0, 0};
    f32x4 acc[4] = {};
    const short* Ab = ebt + (long)z * 36864;     // 288*128
    for (int kh = 0; kh < 2; ++kh) {
      if (kh) __syncthreads();
      for (int u = tid; u < 512; u += 256) {
        int row = u >> 3, c = u & 7;
        int gi = i0 + row;
        bf16x8 vh = vz, vl = vz;
        if (gi < M_) {
          const short* src = &Ab[(long)gi * 128 + kh * 64 + c * 8];
          vh = *(const bf16x8*)src;
          vl = *(const bf16x8*)(src + 147456);
        }
        int dst = row * 64 + ((c ^ (row & 7)) * 8);
        *(bf16x8*)&As[0][dst] = vh;
        *(bf16x8*)&As[1][dst] = vl;
      }
      for (int u = tid; u < 512; u += 256) {
        int row = u >> 3, c = u & 7;
        int gj = j0 + row;
        bf16x8 vh = vz, vl = vz;
        if (gj < M_) {
          const short* src = &Ab[(long)gj * 128 + kh * 64 + c * 8];
          vh = *(const bf16x8*)src;
          vl = *(const bf16x8*)(src + 147456);
        }
        int dst = row * 64 + ((c ^ (row & 7)) * 8);
        *(bf16x8*)&Bs[0][dst] = vh;
        *(bf16x8*)&Bs[1][dst] = vl;
      }
      __syncthreads();
#pragma unroll
      for (int ks = 0; ks < 2; ++ks) {
        const int ch = ks * 4 + kq;
        const int ar = wave * 16 + lr;
        const int ao = ar * 64 + ((ch ^ (ar & 7)) * 8);
        bf16x8 ah = *(const bf16x8*)&As[0][ao];
        bf16x8 al = *(const bf16x8*)&As[1][ao];
#pragma unroll
        for (int ni = 0; ni < 4; ++ni) {
          const int br = ni * 16 + lr;
          const int bo2 = br * 64 + ((ch ^ (br & 7)) * 8);
          bf16x8 bh = *(const bf16x8*)&Bs[0][bo2];
          bf16x8 bl = *(const bf16x8*)&Bs[1][bo2];
          acc[ni] = __builtin_amdgcn_mfma_f32_16x16x32_bf16(ah, bh, acc[ni], 0, 0, 0);
          acc[ni] = __builtin_amdgcn_mfma_f32_16x16x32_bf16(ah, bl, acc[ni], 0, 0, 0);
          acc[ni] = __builtin_amdgcn_mfma_f32_16x16x32_bf16(al, bh, acc[ni], 0, 0, 0);
        }
      }
    }
#pragma unroll
    for (int ni = 0; ni < 4; ++ni) {
      int jg = j0 + ni * 16 + lr;
      if (jg >= M_) continue;
#pragma unroll
      for (int r = 0; r < 4; ++r) {
        int ig = i0 + wave * 16 + kq * 4 + r;
        if (ig >= M_) continue;
        long o = (long)z * 110592 + (long)ig * 384 + jg;   // 288*384
        float v = acc[ni][r];
        short h = f2bf(v);
        pb[o] = h;
        pb[o + 442368] = f2bf(v - bf2f(h));
      }
    }
  }
}

// ------------------------------------------------------------------
// FUSED g_kernel + conv1_aw (independent work, one launch, 576 threads).
// ------------------------------------------------------------------
__global__ __launch_bounds__(576) void g_aw_kernel(
    const float* __restrict__ E, const float* __restrict__ t2,
    const float* __restrict__ w1s, const float* __restrict__ w2s,
    short* __restrict__ Gt,
    const short* __restrict__ w1q, const float* __restrict__ attp,
    short* __restrict__ AWq)
{
  __shared__ float sE[M_], s1[M_], s2[M_];
  __shared__ float sAtt[5][128];
  const int gb = blockIdx.x;
  const int tid = threadIdx.x;

  if (gb < 512) {
    const int s = gb & 127, b = gb >> 7;
    const long base = (long)(b * S_ + s) * M_;
    for (int m = tid; m < M_; m += 576) { sE[m] = E[base + m]; s1[m] = w1s[m]; s2[m] = w2s[m]; }
    __syncthreads();
    const int n = tid >> 1, half = tid & 1;
    const float a = sE[n];
    const float c = t2[base + n];
    float num = 0.f, den = 0.f;
    const int m0 = half * 144;
#pragma unroll 4
    for (int mm = 0; mm < 144; ++mm) {
      int m = m0 + mm;
      float z = fmaf(s1[m], a, s2[m] * c);
      float u = __expf(2.f * z);
      float th = fmaf(-2.f, __builtin_amdgcn_rcpf(u + 1.f), 1.f);
      float e = __expf(th);
      num = fmaf(sE[m], e, num);
      den += e;
    }
    num += __shfl_xor(num, 1, 64);
    den += __shfl_xor(den, 1, 64);
    if (half == 0)
      Gt[((long)(b * 292) + 2 + n) * 128 + s] = f2bf(num / den);
  } else {
    const int j = gb - 512;
    const int half = j & 1;
    const int h = (j >> 1) % 50;
    const int b = (j >> 1) / 50;
    if (tid < 256) {
      for (int u = tid; u < 640; u += 256)
        sAtt[u >> 7][u & 127] = attp[((long)(b * 54) + h + (u >> 7)) * 128 + (u & 127)];
    }
    __syncthreads();
    if (tid < 256) {
      const long obase = ((long)(b * 50 + h) * 80) * 1024;
      for (int u = tid; u < 5120; u += 256) {
        int c = half * 40 + (u >> 7);
        int o = u & 127;
        int dw = c / 16, chq = c & 15;
        float acc[8] = {};
#pragma unroll
        for (int dh = 0; dh < 5; ++dh) {
          bf16x8 wv = *(const bf16x8*)&w1q[(((long)((dh * 5 + dw) * 16 + chq)) * 128 + o) * 8];
          const float* ar = &sAtt[dh][chq * 8];
#pragma unroll
          for (int e = 0; e < 8; ++e) acc[e] = fmaf(bf2f(wv[e]), ar[e], acc[e]);
        }
        union { unsigned u4[4]; bf16x8 v; } pk;
        pk.u4[0] = cvt_pk_bf16(acc[0], acc[1]);
        pk.u4[1] = cvt_pk_bf16(acc[2], acc[3]);
        pk.u4[2] = cvt_pk_bf16(acc[4], acc[5]);
        pk.u4[3] = cvt_pk_bf16(acc[6], acc[7]);
        *(bf16x8*)&AWq[obase + (long)c * 1024 + o * 8] = pk.v;
      }
    }
  }
}

// ------------------------------------------------------------------
// conv1 stage B: per (b,h) GEMM over K=640 (dw,i). BM=128, BN=144.
// ------------------------------------------------------------------
__global__ __launch_bounds__(256) void conv1_mfma(
    const short* __restrict__ AWq, const short* __restrict__ Gt,
    const float* __restrict__ bias, short* __restrict__ y1t)
{
  const int b = blockIdx.z, hrow = blockIdx.y;
  const int w0 = blockIdx.x * 144;
  __shared__ __attribute__((aligned(16))) short Bs[2][148 * 64];
  const int tid = threadIdx.x;
  const int wave = tid >> 6, lane = tid & 63;
  const int lr = lane & 15, kq = lane >> 4;
  f32x4 acc[2][9] = {};

  const short* src = Gt + ((long)(b * 292) + w0) * 128;
  for (int u = tid; u < 2368; u += 256) {
    int row = u >> 4, c = u & 15;
    bf16x8 v = *(const bf16x8*)&src[row * 128 + c * 8];
    *(bf16x8*)&Bs[c >> 3][row * 64 + (((c & 7) ^ (row & 7)) * 8)] = v;
  }
  __syncthreads();

  const long awb = (long)(b * 50 + hrow) * 80;
  for (int dw = 0; dw < 5; ++dw) {
#pragma unroll
    for (int ks = 0; ks < 4; ++ks) {
      const int ch = ks * 4 + kq;
      const long abase = (awb + dw * 16 + ch) * 128 + wave * 32 + lr;
      bf16x8 af0 = *(const bf16x8*)&AWq[abase * 8];
      bf16x8 af1 = *(const bf16x8*)&AWq[(abase + 16) * 8];
      const int arr = ch >> 3, cc = ch & 7;
#pragma unroll
      for (int ni = 0; ni < 9; ++ni) {
        const int row = lr + ni * 16 + dw;
        bf16x8 bfr = *(const bf16x8*)&Bs[arr][row * 64 + ((cc ^ (row & 7)) * 8)];
        acc[0][ni] = __builtin_amdgcn_mfma_f32_16x16x32_bf16(af0, bfr, acc[0][ni], 0, 0, 0);
        acc[1][ni] = __builtin_amdgcn_mfma_f32_16x16x32_bf16(af1, bfr, acc[1][ni], 0, 0, 0);
      }
    }
  }
#pragma unroll
  for (int mi = 0; mi < 2; ++mi) {
    const int og = wave * 32 + mi * 16 + kq * 4;
#pragma unroll
    for (int ni = 0; ni < 9; ++ni) {
      int wg = w0 + ni * 16 + lr;
      short4v pk;
#pragma unroll
      for (int r = 0; r < 4; ++r)
        pk[r] = f2bf(fmaxf(acc[mi][ni][r] + bias[og + r], 0.f));
      *(short4v*)&y1t[(((long)(b * 50) + hrow) * 288 + wg) * 128 + og] = pk;
    }
  }
}

// ------------------------------------------------------------------
// conv2 v5: split-K over dh, pool fused into staging (reads y1t directly).
// ------------------------------------------------------------------
__global__ __launch_bounds__(256) void conv2_dh(
    const short* __restrict__ wq,
    const short* __restrict__ y1t,
    short* __restrict__ y2p)
{
  constexpr int NREP = 3;
  const int bz = blockIdx.z;            // b*5 + dh
  const int b = bz / 5, dh = bz % 5;
  const int hp = blockIdx.y;
  const int w0 = blockIdx.x * 48;
  __shared__ __attribute__((aligned(16))) short Bs[2][52 * 64];
  const int tid = threadIdx.x;
  const int wave = tid >> 6, lane = tid & 63;
  const int lr = lane & 15, kq = lane >> 4;
  const bf16x8 vz = {0, 0, 0, 0, 0, 0, 0, 0};
  f32x4 acc[2][NREP] = {};

  const int rr = hp + dh - 2;           // pooled row index (may be OOB)
  for (int u = tid; u < 832; u += 256) {
    int row = u >> 4, c = u & 15;
    int wp = w0 + row - 2;              // pooled col index (may be OOB)
    bf16x8 v = vz;
    if (rr >= 0 && rr < HP_ && wp >= 0 && wp < WP_) {
      const short* pbase = y1t + (((long)(b * 50 + 2 * rr) * 288) + 2 * wp) * 128 + c * 8;
      bf16x8 v00 = *(const bf16x8*)&pbase[0];
      bf16x8 v01 = *(const bf16x8*)&pbase[128];
      bf16x8 v10 = *(const bf16x8*)&pbase[288 * 128];
      bf16x8 v11 = *(const bf16x8*)&pbase[288 * 128 + 128];
#pragma unroll
      for (int e = 0; e < 8; ++e)
        v[e] = f2bf(fmaxf(fmaxf(bf2f(v00[e]), bf2f(v01[e])),
                          fmaxf(bf2f(v10[e]), bf2f(v11[e]))));
    }
    *(bf16x8*)&Bs[c >> 3][row * 64 + (((c & 7) ^ (row & 7)) * 8)] = v;
  }
  __syncthreads();

#pragma unroll
  for (int dw = 0; dw < 5; ++dw) {
    const int tap = dh * 5 + dw;
#pragma unroll
    for (int ks = 0; ks < 4; ++ks) {
      const int ch = ks * 4 + kq;
      const long abase = ((long)(tap * 16 + ch)) * 128 + wave * 32 + lr;
      bf16x8 af0 = *(const bf16x8*)&wq[abase * 8];
      bf16x8 af1 = *(const bf16x8*)&wq[(abase + 16) * 8];
      const int arr = ch >> 3, cc = ch & 7;
#pragma unroll
      for (int ni = 0; ni < NREP; ++ni) {
        const int row = lr + ni * 16 + dw;
        bf16x8 bfr = *(const bf16x8*)&Bs[arr][row * 64 + ((cc ^ (row & 7)) * 8)];
        acc[0][ni] = __builtin_amdgcn_mfma_f32_16x16x32_bf16(af0, bfr, acc[0][ni], 0, 0, 0);
        acc[1][ni] = __builtin_amdgcn_mfma_f32_16x16x32_bf16(af1, bfr, acc[1][ni], 0, 0, 0);
      }
    }
  }
#pragma unroll
  for (int mi = 0; mi < 2; ++mi) {
    const int og = wave * 32 + mi * 16 + kq * 4;
#pragma unroll
    for (int ni = 0; ni < NREP; ++ni) {
      int wg = w0 + ni * 16 + lr;
#pragma unroll
      for (int r = 0; r < 4; ++r)
        y2p[((long)(dh * 512 + b * 128 + og + r)) * 3600 + hp * 144 + wg] =
            f2bf(acc[mi][ni][r]);
    }
  }
}

// ------------------------------------------------------------------
// tail_fuse: per (b,o): sum partials + bias + relu -> LN(144) -> mean over hp
// ------------------------------------------------------------------
__global__ __launch_bounds__(256) void tail_fuse(
    const short* __restrict__ y2p, const float* __restrict__ bias,
    const float* __restrict__ lng, const float* __restrict__ lnb,
    short* __restrict__ zb)
{
  const int o = blockIdx.x, b = blockIdx.y;
  const int tid = threadIdx.x, wave = tid >> 6, lane = tid & 63;
  __shared__ float sZ[4][3][64];
  float zacc[3] = {0.f, 0.f, 0.f};
  const float bo = bias[o];
  const long base = ((long)(b * 128 + o)) * 3600;
  for (int hp = wave; hp < HP_; hp += 4) {
    float v[3]; float s = 0.f, ss = 0.f;
#pragma unroll
    for (int q = 0; q < 3; ++q) {
      int wp = lane + q * 64;
      float x = 0.f;
      if (wp < WP_) {
        x = bo;
#pragma unroll
        for (int dh = 0; dh < 5; ++dh)
          x += bf2f(y2p[(long)dh * 512 * 3600 + base + hp * 144 + wp]);
        x = fmaxf(x, 0.f);
      }
      v[q] = x; s += x; ss = fmaf(x, x, ss);
    }
#pragma unroll
    for (int off = 32; off; off >>= 1) { s += __shfl_xor(s, off, 64); ss += __shfl_xor(ss, off, 64); }
    float mu = s * (1.f / (float)WP_);
    float var = ss * (1.f / (float)WP_) - mu * mu;
    float inv = rsqrtf(var + 1e-5f);
#pragma unroll
    for (int q = 0; q < 3; ++q) {
      int wp = lane + q * 64;
      if (wp < WP_) zacc[q] += (v[q] - mu) * inv * lng[wp] + lnb[wp];
    }
  }
#pragma unroll
  for (int q = 0; q < 3; ++q) sZ[wave][q][lane] = zacc[q];
  __syncthreads();
  if (wave == 0) {
#pragma unroll
    for (int q = 0; q < 3; ++q) {
      int wp = lane + q * 64;
      if (wp < WP_) {
        float z = (sZ[0][q][lane] + sZ[1][q][lane] + sZ[2][q][lane] + sZ[3][q][lane])
                  * (1.f / (float)HP_);
        long t = (long)(b * 128 + o);
        short h = f2bf(z);
        zb[t * 256 + wp] = h;
        zb[131072 + t * 256 + wp] = f2bf(z - bf2f(h));
      }
    }
  }
}

// ------------------------------------------------------------------
extern "C" void kernel_launch(void* const* d_in, const int* in_sizes, int n_in,
                              void* d_out, int out_size, void* d_ws, size_t ws_size,
                              hipStream_t stream)
{
  const float* bert = (const float*)d_in[0];
  const float* mem  = (const float*)d_in[1];
  const int*   ml   = (const int*)d_in[2];
  const float* cw   = (const float*)d_in[3];
  const int*   ign  = (const int*)d_in[4];
  const float* W1   = (const float*)d_in[6];
  const float* b1l  = (const float*)d_in[7];
  const float* sent = (const float*)d_in[8];
  const float* w1m  = (const float*)d_in[9];
  const float* w2m  = (const float*)d_in[10];
  const float* c1w  = (const float*)d_in[11];
  const float* c1b  = (const float*)d_in[12];
  const float* c2w  = (const float*)d_in[13];
  const float* c2b  = (const float*)d_in[14];
  const float* lng  = (const float*)d_in[15];
  const float* lnb  = (const float*)d_in[16];
  const float* Wo   = (const float*)d_in[17];
  const float* bo   = (const float*)d_in[18];
  float* out = (float*)d_out;

  // ---- A-region (persistent) ----
  short* Gt    = (short*)d_ws;             // 149504
  short* x2t   = Gt + 149504;              // 2197504 (dead buffer, kept for layout)
  short* zb    = x2t + 2197504;            // 262144
  float* attTp = (float*)(zb + 262144);    // 27648 f32
  float* w1s   = attTp + 27648;            // 288
  float* w2s   = w1s + 288;                // 288
  float* ebb   = w2s + 288;                // 1152
  short* wob   = (short*)(ebb + 1152);     // 153600
  short* w1p   = wob + 153600;             // 409600
  short* w2p   = w1p + 409600;             // 409600
  short* y1t   = w2p + 409600;             // 7372800
  // ---- pool X, lifetime-disjoint phases ----
  short* poolX = y1t + 7372800;
  short* bertb = poolX;                    // 786432 (hi+lo)
  short* w1b   = bertb + 786432;           // 442368
  short* ebt   = w1b + 442368;             // 294912 (hi+lo)
  short* Eb    = ebt + 294912;             // 393216
  short* pb    = Eb + 393216;              // 884736
  float* E     = (float*)(pb + 884736);    // 147456 f32
  float* t2    = E + 147456;               // 147456
  short* AWq   = poolX;                    // phase 2 (conv1): 16384000 shorts
  short* y2p   = poolX;                    // phase 3 (conv2 partials): 9216000 shorts

  dim3 blk(256);

  // fused prep: casts + wperms + wsum + in-kernel zeroing
  prep_kernel<<<dim3(4756), blk, 0, stream>>>(
      bert, bertb, W1, w1b, Wo, wob, c1w, w1p, c2w, w2p, w1m, w2m, w1s, w2s,
      (int4*)d_ws, (int4*)Eb);

  // eb = bert @ W1^T + b1  [512x288] K=768; split ebt only
  gemm_split<1><<<dim3(5, 8, 1), blk, 0, stream>>>(
      bertb, w1b, b1l, (float*)nullptr, ebt, 512, 288, 12,
      0L, 768, 393216L, 0L, 768, 221184L, 0L, 288, 0L, 0, 147456L,
      (const int*)nullptr, (const int*)nullptr);

  // ebbar v3: reads s-contiguous split ebt
  ebbar_kernel<<<dim3(5), blk, 0, stream>>>(ebt, ebb);

  // fused score + P-Gram GEMM: 512 score-blocks + 100 P-blocks
  score_p_kernel<<<dim3(612), blk, 0, stream>>>(
      mem, sent, ebb, cw, ml, E, Eb, attTp, ebt, pb);

  // t2 = E @ P  [128x288] K=384(pad)
  gemm_split<0><<<dim3(5, 2, 4), blk, 0, stream>>>(
      Eb, pb, (const float*)nullptr, t2, (short*)nullptr, 128, 288, 6,
      (long)128 * 384, 384, 196608L, (long)288 * 384, 384, 442368L,
      (long)128 * 288, 288, 0L, 0, 0L,
      (const int*)nullptr, (const int*)nullptr);

  // fused g_kernel + conv1_aw: 512 g-blocks + 400 aw-blocks, 576 threads
  g_aw_kernel<<<dim3(912), dim3(576), 0, stream>>>(
      E, t2, w1s, w2s, Gt, w1p, attTp, AWq);

  conv1_mfma<<<dim3(2, 50, 4), blk, 0, stream>>>(AWq, Gt, c1b, y1t);

  // conv2 with fused pooling (reads y1t directly)
  conv2_dh<<<dim3(3, 25, 20), blk, 0, stream>>>(w2p, y1t, y2p);

  // fused: reduce + bias + relu + LN + mean_hp -> zb
  tail_fuse<<<dim3(128, 4), blk, 0, stream>>>(y2p, c2b, lng, lnb, zb);

  // out = z @ W_out^T + b_out, masked  [512x300] K=256(pad)
  gemm_split<3><<<dim3(5, 8, 1), blk, 0, stream>>>(
      zb, wob, bo, out, (short*)nullptr, 512, 300, 4,
      0L, 256, 131072L, 0L, 256, 76800L, 0L, 300, 0L, 0, 0L,
      ml, ign);
}